// Round 4
// baseline (1209.672 us; speedup 1.0000x reference)
//
#include <hip/hip_runtime.h>
#include <math.h>

// EqualityConstraint: x_new = x - J^T G^{-1} F(x)
//   t = tanh(x); s = 1 - t^2; J = A diag(s)
//   F = A t + p; G = A diag(s^2) A^T  (SPD, M x M)
//   y = G^{-1} F;  x_new = x - s .* (A^T y)
//
// One 256-thread block per batch row; 16x16 thread grid, each thread an 8x8
// register tile of G. Blocked right-looking register Cholesky; finished L
// tiles are written to a COMPACT triangular LDS buffer (136 tiles, col-major
// 8x8) so acc is DEAD after phase 4 -- R2/R3 post-mortem: keeping acc live
// through the divergent phase-5 solves makes the allocator spill it to
// scratch (2.9 GB traffic) regardless of the VGPR cap. R1's liveness pattern
// (acc dead post-factorization) allocated cleanly at 128 VGPR.
// The triangular buffer is aliased over the phase-3 stage buffer: LDS ~40 KB
// -> 3 blocks/CU (vs R1's 80 KB -> 2), distributed block solves (vs R1's
// wave-serial solve).

#define kN 256   // x dim
#define kM 128   // constraint dim
#define STP 132  // stage row pitch (floats), 16B-aligned rows
#define RP  8    // reduction-slot pitch
#define TRI(I,K) ((((I) * ((I) + 1)) >> 1) + (K))   // lower-tri tile index, I>=K

__global__ __launch_bounds__(256, 3)
void eqcon_kernel(const float* __restrict__ x,
                  const float* __restrict__ parms,
                  const float* __restrict__ A,
                  float* __restrict__ out)
{
    __shared__ float t_s[kN];
    __shared__ float s_s[kN];
    __shared__ float Fx_s[kM];
    __shared__ float z_s[kM];
    __shared__ float y_s[kM];
    __shared__ float invd_s[kM];
    __shared__ float Ld_s[64];
    __shared__ float red_s[16 * RP];
    // phase 3: A-stage (16*STP = 2112 floats). phase 4+: compact L tiles,
    // tile (I,K) I>=K at TRI(I,K)*64, col-major: T[c*8+r] = L_tile[r][c].
    __shared__ float pool[136 * 64];

    const int tid = (int)threadIdx.x;
    const int b   = (int)blockIdx.x;
    const int ti  = tid & 15;   // row-tile index
    const int tk  = tid >> 4;   // col-tile index

    // ---- Phase 1: t = tanh(x), s = sech^2(x) ----
    const float xv = x[b * kN + tid];
    const float tv = tanhf(xv);
    const float sv = 1.0f - tv * tv;
    t_s[tid] = tv;
    s_s[tid] = sv;
    __syncthreads();

    // ---- Phase 2: Fx = A t + parms (2 threads per row) ----
    {
        const int row  = tid >> 1;
        const int half = tid & 1;
        const float4* __restrict__ Ar =
            reinterpret_cast<const float4*>(A + row * kN + half * (kN / 2));
        const float4* Tr = reinterpret_cast<const float4*>(t_s + half * (kN / 2));
        float sum = 0.0f;
#pragma unroll
        for (int q = 0; q < kN / 8; ++q) {
            const float4 a4 = Ar[q];
            const float4 t4 = Tr[q];
            sum += a4.x * t4.x + a4.y * t4.y + a4.z * t4.z + a4.w * t4.w;
        }
        sum += __shfl_xor(sum, 1);
        if (half == 0) Fx_s[row] = sum + parms[b * kM + row];
    }

    // ---- Phase 3: G = A diag(s^2) A^T, each thread an 8x8 register tile ----
    float acc[8][8];
#pragma unroll
    for (int r = 0; r < 8; ++r)
#pragma unroll
        for (int c = 0; c < 8; ++c) acc[r][c] = 0.0f;

    float* stage = pool;
#pragma unroll 1
    for (int jt = 0; jt < kN; jt += 16) {
        __syncthreads();  // prev tile's compute done before overwriting stage
#pragma unroll
        for (int rep = 0; rep < 8; ++rep) {
            const int idx = rep * 256 + tid;
            const int i   = idx >> 4;
            const int jj  = idx & 15;
            stage[jj * STP + i] = A[i * kN + (jt + jj)];
        }
        __syncthreads();
#pragma unroll
        for (int jj = 0; jj < 16; ++jj) {
            const float sj = s_s[jt + jj];
            const float w  = sj * sj;
            const float* rowp = stage + jj * STP;
            const float4 a0 = *reinterpret_cast<const float4*>(rowp + ti * 8);
            const float4 a1 = *reinterpret_cast<const float4*>(rowp + ti * 8 + 4);
            const float4 b0 = *reinterpret_cast<const float4*>(rowp + tk * 8);
            const float4 b1 = *reinterpret_cast<const float4*>(rowp + tk * 8 + 4);
            const float av[8] = {a0.x * w, a0.y * w, a0.z * w, a0.w * w,
                                 a1.x * w, a1.y * w, a1.z * w, a1.w * w};
            const float bv[8] = {b0.x, b0.y, b0.z, b0.w, b1.x, b1.y, b1.z, b1.w};
#pragma unroll
            for (int r = 0; r < 8; ++r)
#pragma unroll
                for (int c = 0; c < 8; ++c) acc[r][c] += av[r] * bv[c];
        }
    }
    __syncthreads();  // stage reads done; pool becomes the L-tile buffer

    float* Lt = pool;

    // ---- Phase 4: blocked register Cholesky; L tiles published to Lt ----
#pragma unroll 1
    for (int pb = 0; pb < 16; ++pb) {
        const int kb = pb * 8;
        if (ti == pb && tk == pb) {
            // 8x8 diagonal Cholesky in registers (lower triangle)
#pragma unroll
            for (int kk = 0; kk < 8; ++kk) {
                float d = fmaxf(acc[kk][kk], 1e-30f);
                const float rd  = sqrtf(d);
                const float inv = 1.0f / rd;
                invd_s[kb + kk] = inv;
                acc[kk][kk] = rd;
#pragma unroll
                for (int r = kk + 1; r < 8; ++r) acc[r][kk] *= inv;
#pragma unroll
                for (int r = kk + 1; r < 8; ++r)
#pragma unroll
                    for (int c = kk + 1; c <= r; ++c)
                        acc[r][c] -= acc[r][kk] * acc[c][kk];
            }
#pragma unroll
            for (int r = 0; r < 8; ++r)
#pragma unroll
                for (int c = 0; c < 8; ++c) Ld_s[r * 8 + c] = acc[r][c];
            float* T = Lt + TRI(pb, pb) * 64;
#pragma unroll
            for (int c = 0; c < 8; ++c) {
                const float4 lo = make_float4(acc[0][c], acc[1][c], acc[2][c], acc[3][c]);
                const float4 hi = make_float4(acc[4][c], acc[5][c], acc[6][c], acc[7][c]);
                *reinterpret_cast<float4*>(T + c * 8)     = lo;  // upper junk never read
                *reinterpret_cast<float4*>(T + c * 8 + 4) = hi;
            }
        }
        __syncthreads();
        if (tk == pb && ti > pb) {
            // panel solve: B := B * Ld^{-T}; result is final L tile (ti,pb)
#pragma unroll
            for (int c = 0; c < 8; ++c) {
#pragma unroll
                for (int m = 0; m < 8; ++m) {
                    if (m < c) {
                        const float coef = Ld_s[c * 8 + m];
#pragma unroll
                        for (int r = 0; r < 8; ++r) acc[r][c] -= acc[r][m] * coef;
                    }
                }
                const float inv = invd_s[kb + c];
#pragma unroll
                for (int r = 0; r < 8; ++r) acc[r][c] *= inv;
            }
            float* T = Lt + TRI(ti, pb) * 64;
#pragma unroll
            for (int c = 0; c < 8; ++c) {
                const float4 lo = make_float4(acc[0][c], acc[1][c], acc[2][c], acc[3][c]);
                const float4 hi = make_float4(acc[4][c], acc[5][c], acc[6][c], acc[7][c]);
                *reinterpret_cast<float4*>(T + c * 8)     = lo;
                *reinterpret_cast<float4*>(T + c * 8 + 4) = hi;
            }
        }
        __syncthreads();
        if (ti > pb && tk > pb) {
            // rank-8 trailing update from the freshly published panel tiles
            const float* TA = Lt + TRI(ti, pb) * 64;
            const float* TB = Lt + TRI(tk, pb) * 64;
#pragma unroll
            for (int m = 0; m < 8; ++m) {
                const float4 c0 = *reinterpret_cast<const float4*>(TA + m * 8);
                const float4 c1 = *reinterpret_cast<const float4*>(TA + m * 8 + 4);
                const float4 d0 = *reinterpret_cast<const float4*>(TB + m * 8);
                const float4 d1 = *reinterpret_cast<const float4*>(TB + m * 8 + 4);
                const float cl[8] = {c0.x, c0.y, c0.z, c0.w, c1.x, c1.y, c1.z, c1.w};
                const float cc[8] = {d0.x, d0.y, d0.z, d0.w, d1.x, d1.y, d1.z, d1.w};
#pragma unroll
                for (int r = 0; r < 8; ++r)
#pragma unroll
                    for (int c = 0; c < 8; ++c) acc[r][c] -= cl[r] * cc[c];
            }
        }
        // no barrier needed: barrier 1 of next iter orders Ld_s/Lt reuse
    }
    __syncthreads();
    // acc is DEAD from here on -- allocator can reuse its 64 registers.

    // ---- Phase 5a: forward block solve L z = Fx (tiles from Lt) ----
#pragma unroll 1
    for (int I = 0; I < 16; ++I) {
        if (ti == I && tk < I) {
            // u = L(I,tk) * z[tk-block]
            const float* T = Lt + TRI(I, tk) * 64;
            const float4 z0 = *reinterpret_cast<const float4*>(z_s + tk * 8);
            const float4 z1 = *reinterpret_cast<const float4*>(z_s + tk * 8 + 4);
            const float zc[8] = {z0.x, z0.y, z0.z, z0.w, z1.x, z1.y, z1.z, z1.w};
            float u[8];
#pragma unroll
            for (int r = 0; r < 8; ++r) u[r] = 0.0f;
#pragma unroll
            for (int c = 0; c < 8; ++c) {
                const float4 lo = *reinterpret_cast<const float4*>(T + c * 8);
                const float4 hi = *reinterpret_cast<const float4*>(T + c * 8 + 4);
                u[0] += lo.x * zc[c]; u[1] += lo.y * zc[c];
                u[2] += lo.z * zc[c]; u[3] += lo.w * zc[c];
                u[4] += hi.x * zc[c]; u[5] += hi.y * zc[c];
                u[6] += hi.z * zc[c]; u[7] += hi.w * zc[c];
            }
#pragma unroll
            for (int r = 0; r < 8; ++r) red_s[tk * RP + r] = u[r];
        }
        __syncthreads();
        if (ti == I && tk == I) {
            const float* T = Lt + TRI(I, I) * 64;
            float w[8];
#pragma unroll
            for (int r = 0; r < 8; ++r) w[r] = Fx_s[I * 8 + r];
            for (int K = 0; K < I; ++K)
#pragma unroll
                for (int r = 0; r < 8; ++r) w[r] -= red_s[K * RP + r];
            float zl[8];
#pragma unroll
            for (int r = 0; r < 8; ++r) {
                float v = w[r];
#pragma unroll
                for (int m = 0; m < 8; ++m)
                    if (m < r) v -= T[m * 8 + r] * zl[m];
                zl[r] = v * invd_s[I * 8 + r];
                z_s[I * 8 + r] = zl[r];
            }
        }
        __syncthreads();
    }

    // ---- Phase 5b: backward block solve L^T y = z (tiles from Lt) ----
#pragma unroll 1
    for (int K = 15; K >= 0; --K) {
        if (tk == K && ti > K) {
            // u = L(ti,K)^T * y[ti-block]
            const float* T = Lt + TRI(ti, K) * 64;
            const float4 y0 = *reinterpret_cast<const float4*>(y_s + ti * 8);
            const float4 y1 = *reinterpret_cast<const float4*>(y_s + ti * 8 + 4);
            const float yl[8] = {y0.x, y0.y, y0.z, y0.w, y1.x, y1.y, y1.z, y1.w};
#pragma unroll
            for (int c = 0; c < 8; ++c) {
                const float4 lo = *reinterpret_cast<const float4*>(T + c * 8);
                const float4 hi = *reinterpret_cast<const float4*>(T + c * 8 + 4);
                const float u = lo.x * yl[0] + lo.y * yl[1] + lo.z * yl[2] + lo.w * yl[3]
                              + hi.x * yl[4] + hi.y * yl[5] + hi.z * yl[6] + hi.w * yl[7];
                red_s[ti * RP + c] = u;
            }
        }
        __syncthreads();
        if (ti == K && tk == K) {
            const float* T = Lt + TRI(K, K) * 64;
            float w[8];
#pragma unroll
            for (int c = 0; c < 8; ++c) w[c] = z_s[K * 8 + c];
            for (int I = K + 1; I < 16; ++I)
#pragma unroll
                for (int c = 0; c < 8; ++c) w[c] -= red_s[I * RP + c];
            float yl[8];
#pragma unroll
            for (int cc = 0; cc < 8; ++cc) {
                const int c = 7 - cc;
                float v = w[c];
#pragma unroll
                for (int m = 0; m < 8; ++m)
                    if (m > c) v -= T[c * 8 + m] * yl[m];
                yl[c] = v * invd_s[K * 8 + c];
                y_s[K * 8 + c] = yl[c];
            }
        }
        __syncthreads();
    }

    // ---- Phase 6: x_new = x - s .* (A^T y) (coalesced over columns) ----
    {
        float sum = 0.0f;
#pragma unroll 8
        for (int i = 0; i < kM; ++i) sum += A[i * kN + tid] * y_s[i];
        out[b * kN + tid] = xv - sv * sum;
    }
}

extern "C" void kernel_launch(void* const* d_in, const int* in_sizes, int n_in,
                              void* d_out, int out_size, void* d_ws, size_t ws_size,
                              hipStream_t stream) {
    const float* x     = (const float*)d_in[0];
    const float* parms = (const float*)d_in[1];
    const float* A     = (const float*)d_in[2];
    float* out = (float*)d_out;
    const int Bcount = in_sizes[0] / kN;  // 2048
    eqcon_kernel<<<dim3(Bcount), dim3(256), 0, stream>>>(x, parms, A, out);
}

// Round 5
// 826.351 us; speedup vs baseline: 1.4639x; 1.4639x over previous
//
#include <hip/hip_runtime.h>
#include <math.h>

// EqualityConstraint: x_new = x - J^T G^{-1} F(x)
//   t = tanh(x); s = 1 - t^2; J = A diag(s)
//   F = A t + p; G = A diag(s^2) A^T  (SPD, M x M)
//   y = G^{-1} F;  x_new = x - s .* (A^T y)
//
// One 256-thread block per batch row; 16x16 thread grid, each thread an 8x8
// register tile of G -> L (blocked right-looking register Cholesky).
// Finished L tiles go to a compact triangular LDS buffer (136 tiles,
// col-major 8x8), aliased over the phase-3 A-stage: LDS ~40 KB.
// Distributed block triangular solves read tiles from LDS.
//
// SPILL POST-MORTEM (R2-R4): `#pragma unroll 1` on the jt/pb loops made
// acc[8][8] a rolled-loop-carried live range across divergent branches;
// the allocator spilled it around every iteration (VGPR 84, 1.5-5 GB
// scratch traffic) REGARDLESS of launch-bound headroom. R1's plain `for`
// (compiler fully unrolls, straight-line liveness) allocated cleanly at
// 128 VGPR with zero scratch. NEVER force-roll a loop that carries a
// large register array on gfx950. Launch bounds (256,2) as in R1; with
// VGPR<=128 the 40 KB LDS gives 4 blocks/CU (50% occupancy).

#define kN 256   // x dim
#define kM 128   // constraint dim
#define STP 132  // stage row pitch (floats), 16B-aligned rows
#define RP  8    // reduction-slot pitch
#define TRI(I,K) ((((I) * ((I) + 1)) >> 1) + (K))   // lower-tri tile index, I>=K

__global__ __launch_bounds__(256, 2)
void eqcon_kernel(const float* __restrict__ x,
                  const float* __restrict__ parms,
                  const float* __restrict__ A,
                  float* __restrict__ out)
{
    __shared__ float t_s[kN];
    __shared__ float s_s[kN];
    __shared__ float Fx_s[kM];
    __shared__ float z_s[kM];
    __shared__ float y_s[kM];
    __shared__ float invd_s[kM];
    __shared__ float Ld_s[64];
    __shared__ float red_s[16 * RP];
    // phase 3: A-stage (16*STP = 2112 floats). phase 4+: compact L tiles,
    // tile (I,K) I>=K at TRI(I,K)*64, col-major: T[c*8+r] = L_tile[r][c].
    __shared__ float pool[136 * 64];

    const int tid = (int)threadIdx.x;
    const int b   = (int)blockIdx.x;
    const int ti  = tid & 15;   // row-tile index
    const int tk  = tid >> 4;   // col-tile index

    // ---- Phase 1: t = tanh(x), s = sech^2(x) ----
    const float xv = x[b * kN + tid];
    const float tv = tanhf(xv);
    const float sv = 1.0f - tv * tv;
    t_s[tid] = tv;
    s_s[tid] = sv;
    __syncthreads();

    // ---- Phase 2: Fx = A t + parms (2 threads per row) ----
    {
        const int row  = tid >> 1;
        const int half = tid & 1;
        const float4* __restrict__ Ar =
            reinterpret_cast<const float4*>(A + row * kN + half * (kN / 2));
        const float4* Tr = reinterpret_cast<const float4*>(t_s + half * (kN / 2));
        float sum = 0.0f;
#pragma unroll
        for (int q = 0; q < kN / 8; ++q) {
            const float4 a4 = Ar[q];
            const float4 t4 = Tr[q];
            sum += a4.x * t4.x + a4.y * t4.y + a4.z * t4.z + a4.w * t4.w;
        }
        sum += __shfl_xor(sum, 1);
        if (half == 0) Fx_s[row] = sum + parms[b * kM + row];
    }

    // ---- Phase 3: G = A diag(s^2) A^T, each thread an 8x8 register tile ----
    float acc[8][8];
#pragma unroll
    for (int r = 0; r < 8; ++r)
#pragma unroll
        for (int c = 0; c < 8; ++c) acc[r][c] = 0.0f;

    float* stage = pool;
    for (int jt = 0; jt < kN; jt += 16) {
        __syncthreads();  // prev tile's compute done before overwriting stage
#pragma unroll
        for (int rep = 0; rep < 8; ++rep) {
            const int idx = rep * 256 + tid;
            const int i   = idx >> 4;
            const int jj  = idx & 15;
            stage[jj * STP + i] = A[i * kN + (jt + jj)];
        }
        __syncthreads();
#pragma unroll
        for (int jj = 0; jj < 16; ++jj) {
            const float sj = s_s[jt + jj];
            const float w  = sj * sj;
            const float* rowp = stage + jj * STP;
            const float4 a0 = *reinterpret_cast<const float4*>(rowp + ti * 8);
            const float4 a1 = *reinterpret_cast<const float4*>(rowp + ti * 8 + 4);
            const float4 b0 = *reinterpret_cast<const float4*>(rowp + tk * 8);
            const float4 b1 = *reinterpret_cast<const float4*>(rowp + tk * 8 + 4);
            const float av[8] = {a0.x, a0.y, a0.z, a0.w, a1.x, a1.y, a1.z, a1.w};
            const float bv[8] = {b0.x * w, b0.y * w, b0.z * w, b0.w * w,
                                 b1.x * w, b1.y * w, b1.z * w, b1.w * w};
#pragma unroll
            for (int r = 0; r < 8; ++r)
#pragma unroll
                for (int c = 0; c < 8; ++c) acc[r][c] += av[r] * bv[c];
        }
    }
    __syncthreads();  // stage reads done; pool becomes the L-tile buffer

    float* Lt = pool;

    // ---- Phase 4: blocked register Cholesky; L tiles published to Lt ----
    for (int pb = 0; pb < 16; ++pb) {
        const int kb = pb * 8;
        if (ti == pb && tk == pb) {
            // 8x8 diagonal Cholesky in registers (lower triangle)
#pragma unroll
            for (int kk = 0; kk < 8; ++kk) {
                float d = fmaxf(acc[kk][kk], 1e-30f);
                const float rd  = sqrtf(d);
                const float inv = 1.0f / rd;
                invd_s[kb + kk] = inv;
                acc[kk][kk] = rd;
#pragma unroll
                for (int r = kk + 1; r < 8; ++r) acc[r][kk] *= inv;
#pragma unroll
                for (int r = kk + 1; r < 8; ++r)
#pragma unroll
                    for (int c = kk + 1; c <= r; ++c)
                        acc[r][c] -= acc[r][kk] * acc[c][kk];
            }
#pragma unroll
            for (int r = 0; r < 8; ++r)
#pragma unroll
                for (int c = 0; c < 8; ++c) Ld_s[r * 8 + c] = acc[r][c];
            float* T = Lt + TRI(pb, pb) * 64;
#pragma unroll
            for (int c = 0; c < 8; ++c) {
                const float4 lo = make_float4(acc[0][c], acc[1][c], acc[2][c], acc[3][c]);
                const float4 hi = make_float4(acc[4][c], acc[5][c], acc[6][c], acc[7][c]);
                *reinterpret_cast<float4*>(T + c * 8)     = lo;  // upper junk never read
                *reinterpret_cast<float4*>(T + c * 8 + 4) = hi;
            }
        }
        __syncthreads();
        if (tk == pb && ti > pb) {
            // panel solve: B := B * Ld^{-T}; result is final L tile (ti,pb)
#pragma unroll
            for (int c = 0; c < 8; ++c) {
#pragma unroll
                for (int m = 0; m < 8; ++m) {
                    if (m < c) {
                        const float coef = Ld_s[c * 8 + m];
#pragma unroll
                        for (int r = 0; r < 8; ++r) acc[r][c] -= acc[r][m] * coef;
                    }
                }
                const float inv = invd_s[kb + c];
#pragma unroll
                for (int r = 0; r < 8; ++r) acc[r][c] *= inv;
            }
            float* T = Lt + TRI(ti, pb) * 64;
#pragma unroll
            for (int c = 0; c < 8; ++c) {
                const float4 lo = make_float4(acc[0][c], acc[1][c], acc[2][c], acc[3][c]);
                const float4 hi = make_float4(acc[4][c], acc[5][c], acc[6][c], acc[7][c]);
                *reinterpret_cast<float4*>(T + c * 8)     = lo;
                *reinterpret_cast<float4*>(T + c * 8 + 4) = hi;
            }
        }
        __syncthreads();
        if (ti > pb && tk > pb) {
            // rank-8 trailing update from the freshly published panel tiles
            const float* TA = Lt + TRI(ti, pb) * 64;
            const float* TB = Lt + TRI(tk, pb) * 64;
#pragma unroll
            for (int m = 0; m < 8; ++m) {
                const float4 c0 = *reinterpret_cast<const float4*>(TA + m * 8);
                const float4 c1 = *reinterpret_cast<const float4*>(TA + m * 8 + 4);
                const float4 d0 = *reinterpret_cast<const float4*>(TB + m * 8);
                const float4 d1 = *reinterpret_cast<const float4*>(TB + m * 8 + 4);
                const float cl[8] = {c0.x, c0.y, c0.z, c0.w, c1.x, c1.y, c1.z, c1.w};
                const float cc[8] = {d0.x, d0.y, d0.z, d0.w, d1.x, d1.y, d1.z, d1.w};
#pragma unroll
                for (int r = 0; r < 8; ++r)
#pragma unroll
                    for (int c = 0; c < 8; ++c) acc[r][c] -= cl[r] * cc[c];
            }
        }
        // no barrier needed: barrier 1 of next iter orders Ld_s/Lt reuse
    }
    __syncthreads();
    // acc is DEAD from here on.

    // ---- Phase 5a: forward block solve L z = Fx (tiles from Lt) ----
    for (int I = 0; I < 16; ++I) {
        if (ti == I && tk < I) {
            // u = L(I,tk) * z[tk-block]
            const float* T = Lt + TRI(I, tk) * 64;
            const float4 z0 = *reinterpret_cast<const float4*>(z_s + tk * 8);
            const float4 z1 = *reinterpret_cast<const float4*>(z_s + tk * 8 + 4);
            const float zc[8] = {z0.x, z0.y, z0.z, z0.w, z1.x, z1.y, z1.z, z1.w};
            float u[8];
#pragma unroll
            for (int r = 0; r < 8; ++r) u[r] = 0.0f;
#pragma unroll
            for (int c = 0; c < 8; ++c) {
                const float4 lo = *reinterpret_cast<const float4*>(T + c * 8);
                const float4 hi = *reinterpret_cast<const float4*>(T + c * 8 + 4);
                u[0] += lo.x * zc[c]; u[1] += lo.y * zc[c];
                u[2] += lo.z * zc[c]; u[3] += lo.w * zc[c];
                u[4] += hi.x * zc[c]; u[5] += hi.y * zc[c];
                u[6] += hi.z * zc[c]; u[7] += hi.w * zc[c];
            }
#pragma unroll
            for (int r = 0; r < 8; ++r) red_s[tk * RP + r] = u[r];
        }
        __syncthreads();
        if (ti == I && tk == I) {
            const float* T = Lt + TRI(I, I) * 64;
            float w[8];
#pragma unroll
            for (int r = 0; r < 8; ++r) w[r] = Fx_s[I * 8 + r];
            for (int K = 0; K < I; ++K)
#pragma unroll
                for (int r = 0; r < 8; ++r) w[r] -= red_s[K * RP + r];
            float zl[8];
#pragma unroll
            for (int r = 0; r < 8; ++r) {
                float v = w[r];
#pragma unroll
                for (int m = 0; m < 8; ++m)
                    if (m < r) v -= T[m * 8 + r] * zl[m];
                zl[r] = v * invd_s[I * 8 + r];
                z_s[I * 8 + r] = zl[r];
            }
        }
        __syncthreads();
    }

    // ---- Phase 5b: backward block solve L^T y = z (tiles from Lt) ----
    for (int K = 15; K >= 0; --K) {
        if (tk == K && ti > K) {
            // u = L(ti,K)^T * y[ti-block]
            const float* T = Lt + TRI(ti, K) * 64;
            const float4 y0 = *reinterpret_cast<const float4*>(y_s + ti * 8);
            const float4 y1 = *reinterpret_cast<const float4*>(y_s + ti * 8 + 4);
            const float yl[8] = {y0.x, y0.y, y0.z, y0.w, y1.x, y1.y, y1.z, y1.w};
#pragma unroll
            for (int c = 0; c < 8; ++c) {
                const float4 lo = *reinterpret_cast<const float4*>(T + c * 8);
                const float4 hi = *reinterpret_cast<const float4*>(T + c * 8 + 4);
                const float u = lo.x * yl[0] + lo.y * yl[1] + lo.z * yl[2] + lo.w * yl[3]
                              + hi.x * yl[4] + hi.y * yl[5] + hi.z * yl[6] + hi.w * yl[7];
                red_s[ti * RP + c] = u;
            }
        }
        __syncthreads();
        if (ti == K && tk == K) {
            const float* T = Lt + TRI(K, K) * 64;
            float w[8];
#pragma unroll
            for (int c = 0; c < 8; ++c) w[c] = z_s[K * 8 + c];
            for (int I = K + 1; I < 16; ++I)
#pragma unroll
                for (int c = 0; c < 8; ++c) w[c] -= red_s[I * RP + c];
            float yl[8];
#pragma unroll
            for (int cc = 0; cc < 8; ++cc) {
                const int c = 7 - cc;
                float v = w[c];
#pragma unroll
                for (int m = 0; m < 8; ++m)
                    if (m > c) v -= T[c * 8 + m] * yl[m];
                yl[c] = v * invd_s[K * 8 + c];
                y_s[K * 8 + c] = yl[c];
            }
        }
        __syncthreads();
    }

    // ---- Phase 6: x_new = x - s .* (A^T y) (coalesced over columns) ----
    {
        float sum = 0.0f;
#pragma unroll 8
        for (int i = 0; i < kM; ++i) sum += A[i * kN + tid] * y_s[i];
        out[b * kN + tid] = xv - sv * sum;
    }
}

extern "C" void kernel_launch(void* const* d_in, const int* in_sizes, int n_in,
                              void* d_out, int out_size, void* d_ws, size_t ws_size,
                              hipStream_t stream) {
    const float* x     = (const float*)d_in[0];
    const float* parms = (const float*)d_in[1];
    const float* A     = (const float*)d_in[2];
    float* out = (float*)d_out;
    const int Bcount = in_sizes[0] / kN;  // 2048
    eqcon_kernel<<<dim3(Bcount), dim3(256), 0, stream>>>(x, parms, A, out);
}